// Round 2
// baseline (475.248 us; speedup 1.0000x reference)
//
#include <hip/hip_runtime.h>
#include <math.h>

#define DD 128            // feature dim
#define KNB 20            // neighbors per node
#define K3 384            // 3*D
#define ROWS 16           // rows (nodes) per fused block

typedef unsigned short u16;
typedef __attribute__((ext_vector_type(8))) short short8;   // 8 bf16 = 4 VGPRs
typedef __attribute__((ext_vector_type(4))) float f32x4;

// f32 -> bf16 round-to-nearest-even
static __device__ __forceinline__ u16 f2bf(float x) {
    union { float f; unsigned u; } v; v.f = x;
    unsigned r = v.u + 0x7fffu + ((v.u >> 16) & 1u);
    return (u16)(r >> 16);
}

// bf16 -> f32 (exact)
static __device__ __forceinline__ float bf2f(u16 h) {
    union { unsigned u; float f; } v; v.u = ((unsigned)h) << 16;
    return v.f;
}

// fast cos: v_fract + v_cos_f32 (input in revolutions). Phase granularity at
// |x|~1e4 rad is ~1.2e-4 rev -> cos abs err ~7.5e-4, far below the bf16
// quantization (0.0625 at magnitude 20) already in the AGG path.
static __device__ __forceinline__ float fcos(float x) {
    float r = x * 0.15915494309189535f;       // 1/(2*pi)
    r = __builtin_amdgcn_fractf(r);
    return __builtin_amdgcn_cosf(r);
}

static __device__ __forceinline__ void st4bf(u16* p, float4 v) {
    ushort4 s;
    s.x = f2bf(v.x); s.y = f2bf(v.y); s.z = f2bf(v.z); s.w = f2bf(v.w);
    *(ushort4*)p = s;
}

// ---------------------------------------------------------------------------
// Prep: blocks 0..39 pack W1 (384x128) and W2 rows 0..255 into MFMA B-fragment
// order (bf16). Block 40 computes cvec[d] = b2[d] + sum_i cos(tb[i])*W2[2D+i][d].
// Blocks 41.. convert the node-feature table to bf16 (nfb16[N][128]) so the
// gather phase moves 256B rows instead of 512B (fabric-byte bound).
// For 16x16x32: lane L holds B[k0 + (L>>4)*8 + j][ct*16 + (L&15)], j=0..7,
// stored contiguously (16B per lane) at [ktile][ct][L][8].
// ---------------------------------------------------------------------------
__global__ __launch_bounds__(256) void prep_kernel(
    const float* __restrict__ W1, const float* __restrict__ W2,
    const float* __restrict__ tb, const float* __restrict__ b2,
    const float* __restrict__ nodef,
    u16* __restrict__ W1p, u16* __restrict__ W2p, float* __restrict__ cvec,
    u16* __restrict__ nfb16, int N)
{
    const int tid = threadIdx.x;
    const int bx  = blockIdx.x;
    if (bx < 40) {
        int t = bx * 256 + tid;
        if (t < 6144) {                       // W1: 12 * 8 * 64
            int L = t & 63;
            int ct = (t >> 6) & 7;
            int kt = t >> 9;
            int n  = ct * 16 + (L & 15);
            int kb = kt * 32 + (L >> 4) * 8;
            u16* d = W1p + (size_t)t * 8;
            #pragma unroll
            for (int j = 0; j < 8; ++j) d[j] = f2bf(W1[(size_t)(kb + j) * DD + n]);
        } else if (t < 10240) {               // W2 parts 0,1: 2 * 4 * 8 * 64
            int u = t - 6144;
            int L = u & 63;
            int ct = (u >> 6) & 7;
            int kt = (u >> 9) & 3;
            int part = u >> 11;
            int n  = ct * 16 + (L & 15);
            int kb = part * DD + kt * 32 + (L >> 4) * 8;
            u16* d = W2p + (size_t)u * 8;
            #pragma unroll
            for (int j = 0; j < 8; ++j) d[j] = f2bf(W2[(size_t)(kb + j) * DD + n]);
        }
    } else if (bx == 40) {
        __shared__ float red[DD];
        int d = tid & (DD - 1);
        int h = tid >> 7;                     // 0 or 1: each sums 64 terms
        float acc = 0.f;
        int i0 = h * 64;
        #pragma unroll 8
        for (int i = i0; i < i0 + 64; ++i)
            acc = fmaf(cosf(tb[i]), W2[(size_t)(2 * DD + i) * DD + d], acc);
        if (h) red[d] = acc;
        __syncthreads();
        if (!h) cvec[d] = acc + red[d] + b2[d];
    } else {
        // bf16-ify node features: 2 float4 -> ushort4 per thread, coalesced
        const float4* src = (const float4*)nodef;
        int total4 = N * (DD / 4);            // # float4 in the table
        int base   = (bx - 41) * 256 + tid;
        int stride = ((total4 / 2) + 255) & ~255;   // half, rounded to grid
        #pragma unroll
        for (int rep = 0; rep < 2; ++rep) {
            int idx = base + rep * stride;
            if (idx < total4) {
                float4 v = src[idx];
                st4bf(nfb16 + (size_t)idx * 4, v);
            }
        }
    }
}

// ---------------------------------------------------------------------------
// Fused kernel: 16 nodes/block, 256 threads = 4 waves, grid = ceil(N/16).
//  Phase G (gather): 8 groups of 32 lanes; each group owns nodes g and g+8.
//    Node rows come from the bf16 table (256B, ushort4/lane); edge rows from
//    f32 edgef (512B, float4/lane). cos via v_fract+v_cos. Accumulators in
//    registers; deposited to LDS as bf16 AGG tile [16][384] + NF tile [16][128].
//  Phase 1: H = relu(AGG @ W1 + 20*b1) -> bf16 back into the AGG LDS region.
//  Phase 2: out = H @ W2[0:128] + NF @ W2[128:256] + cvec.
// ---------------------------------------------------------------------------
#define APITCH 392      // bf16 elems; 784B rows: 16B-aligned, stride==4 mod 32 banks
#define HPITCH 136      // 272B rows: 16B-aligned, stride==4 mod 32 banks

__global__ __launch_bounds__(256, 4) void fused_all(
    const u16* __restrict__ nfb16, const float* __restrict__ ts,
    const float* __restrict__ edgef, const int* __restrict__ neighbors,
    const int* __restrict__ edge_idxs, const float* __restrict__ edge_times,
    const float* __restrict__ tw, const float* __restrict__ tb,
    const u16* __restrict__ W1p, const u16* __restrict__ W2p,
    const float* __restrict__ b1, const float* __restrict__ cvec,
    float* __restrict__ out, int N)
{
    __shared__ __align__(16) u16 As[ROWS * APITCH];     // 12544 B; reused as Hs
    __shared__ __align__(16) u16 NFs[ROWS * HPITCH];    //  4352 B
    __shared__ int   s_nb[ROWS * KNB];
    __shared__ int   s_eg[ROWS * KNB];
    __shared__ float s_dt[ROWS * KNB];

    const int tid  = threadIdx.x;
    const int row0 = blockIdx.x * ROWS;

    // ---- stage indices / deltas (coalesced: idx runs contiguously) ----
    for (int idx = tid; idx < ROWS * KNB; idx += 256) {
        int nsub = idx / KNB;
        int k    = idx - nsub * KNB;
        int nn   = row0 + nsub;
        if (nn < N) {
            s_nb[idx] = neighbors[(size_t)nn * KNB + k];
            s_eg[idx] = edge_idxs[(size_t)nn * KNB + k];
            s_dt[idx] = ts[nn] - edge_times[(size_t)nn * KNB + k];
        } else {
            s_nb[idx] = 0; s_eg[idx] = 0; s_dt[idx] = 0.f;
        }
    }
    __syncthreads();

    // ---- phase G: gather + time-encode, 2 interleaved nodes per group ----
    {
        const int c  = tid & 31;
        const int g  = tid >> 5;
        const int ra = g, rb = g + 8;

        const ushort4* nb16 = (const ushort4*)nfb16;   // bf16 row = 32 ushort4
        const float4*  ef4  = (const float4*)edgef;
        const float4   w4   = ((const float4*)tw)[c];
        const float4   b4   = ((const float4*)tb)[c];

        const int*   nba = s_nb + ra * KNB;
        const int*   ega = s_eg + ra * KNB;
        const float* dpa = s_dt + ra * KNB;
        const int*   nbb = s_nb + rb * KNB;
        const int*   egb = s_eg + rb * KNB;
        const float* dpb = s_dt + rb * KNB;

        float4 z = make_float4(0.f, 0.f, 0.f, 0.f);
        float4 ana = z, aea = z, ata = z;
        float4 anb = z, aeb = z, atb = z;

        #pragma unroll 4
        for (int k = 0; k < KNB; ++k) {
            int   nia = nba[k], eia = ega[k];
            int   nib = nbb[k], eib = egb[k];
            float dta = dpa[k], dtb = dpb[k];
            ushort4 nva = nb16[(size_t)nia * 32 + c];
            float4  eva = ef4[(size_t)eia * 32 + c];
            ushort4 nvb = nb16[(size_t)nib * 32 + c];
            float4  evb = ef4[(size_t)eib * 32 + c];
            ana.x += bf2f(nva.x); ana.y += bf2f(nva.y);
            ana.z += bf2f(nva.z); ana.w += bf2f(nva.w);
            aea.x += eva.x; aea.y += eva.y; aea.z += eva.z; aea.w += eva.w;
            anb.x += bf2f(nvb.x); anb.y += bf2f(nvb.y);
            anb.z += bf2f(nvb.z); anb.w += bf2f(nvb.w);
            aeb.x += evb.x; aeb.y += evb.y; aeb.z += evb.z; aeb.w += evb.w;
            ata.x += fcos(fmaf(dta, w4.x, b4.x));
            ata.y += fcos(fmaf(dta, w4.y, b4.y));
            ata.z += fcos(fmaf(dta, w4.z, b4.z));
            ata.w += fcos(fmaf(dta, w4.w, b4.w));
            atb.x += fcos(fmaf(dtb, w4.x, b4.x));
            atb.y += fcos(fmaf(dtb, w4.y, b4.y));
            atb.z += fcos(fmaf(dtb, w4.z, b4.z));
            atb.w += fcos(fmaf(dtb, w4.w, b4.w));
        }

        u16* oa = As + ra * APITCH;
        st4bf(oa + 4 * c,          ana);
        st4bf(oa + DD + 4 * c,     ata);
        st4bf(oa + 2 * DD + 4 * c, aea);
        u16* ob = As + rb * APITCH;
        st4bf(ob + 4 * c,          anb);
        st4bf(ob + DD + 4 * c,     atb);
        st4bf(ob + 2 * DD + 4 * c, aeb);

        // self node-feature rows (already bf16) straight into NFs
        ushort4 z4 = make_ushort4(0, 0, 0, 0);
        int na = row0 + ra;
        ushort4 sa = (na < N) ? nb16[(size_t)na * 32 + c] : z4;
        *(ushort4*)&NFs[ra * HPITCH + 4 * c] = sa;
        int nb_ = row0 + rb;
        ushort4 sb = (nb_ < N) ? nb16[(size_t)nb_ * 32 + c] : z4;
        *(ushort4*)&NFs[rb * HPITCH + 4 * c] = sb;
    }
    __syncthreads();

    // ---- phase 1: AGG @ W1 ; wave w owns ct = {2w, 2w+1}, full 16-row M ----
    const int lane = tid & 63;
    const int wave = tid >> 6;
    const int l15  = lane & 15;
    const int quad = lane >> 4;
    const int ct0  = wave * 2;

    f32x4 acc[2];
    acc[0] = (f32x4){0.f, 0.f, 0.f, 0.f};
    acc[1] = (f32x4){0.f, 0.f, 0.f, 0.f};

    const short8* W1v = (const short8*)W1p;
    for (int kt = 0; kt < 12; ++kt) {
        short8 a = *(const short8*)&As[l15 * APITCH + kt * 32 + quad * 8];
        #pragma unroll
        for (int cc = 0; cc < 2; ++cc) {
            short8 b = W1v[(size_t)(kt * 8 + ct0 + cc) * 64 + lane];
            acc[cc] = __builtin_amdgcn_mfma_f32_16x16x32_bf16(a, b, acc[cc], 0, 0, 0);
        }
    }
    __syncthreads();    // all waves done reading As

    // ---- epilogue 1: bias+relu -> Hs (bf16, reuses As region) ----
    u16* Hs = As;
    #pragma unroll
    for (int cc = 0; cc < 2; ++cc) {
        int col = (ct0 + cc) * 16 + l15;
        float bb = (float)KNB * b1[col];
        #pragma unroll
        for (int r = 0; r < 4; ++r) {
            float h = acc[cc][r] + bb;          // C/D: col=lane&15, row=quad*4+r
            h = h > 0.f ? h : 0.f;
            Hs[(quad * 4 + r) * HPITCH + col] = f2bf(h);
        }
    }
    __syncthreads();

    // ---- phase 2: H@W2a + NF@W2b + cvec ----
    f32x4 acc2[2];
    #pragma unroll
    for (int cc = 0; cc < 2; ++cc) {
        float cv = cvec[(ct0 + cc) * 16 + l15];
        acc2[cc] = (f32x4){cv, cv, cv, cv};
    }
    const short8* W2v = (const short8*)W2p;
    for (int kt = 0; kt < 4; ++kt) {
        short8 aH = *(const short8*)&Hs[l15 * HPITCH + kt * 32 + quad * 8];
        #pragma unroll
        for (int cc = 0; cc < 2; ++cc) {
            short8 b = W2v[(size_t)(kt * 8 + ct0 + cc) * 64 + lane];
            acc2[cc] = __builtin_amdgcn_mfma_f32_16x16x32_bf16(aH, b, acc2[cc], 0, 0, 0);
        }
        short8 aN = *(const short8*)&NFs[l15 * HPITCH + kt * 32 + quad * 8];
        #pragma unroll
        for (int cc = 0; cc < 2; ++cc) {
            short8 b = W2v[(size_t)((4 + kt) * 8 + ct0 + cc) * 64 + lane];
            acc2[cc] = __builtin_amdgcn_mfma_f32_16x16x32_bf16(aN, b, acc2[cc], 0, 0, 0);
        }
    }

    // ---- store ----
    #pragma unroll
    for (int cc = 0; cc < 2; ++cc) {
        int col = (ct0 + cc) * 16 + l15;
        #pragma unroll
        for (int r = 0; r < 4; ++r) {
            int row = row0 + quad * 4 + r;
            if (row < N) out[(size_t)row * DD + col] = acc2[cc][r];
        }
    }
}

// ---------------------------------------------------------------------------
extern "C" void kernel_launch(void* const* d_in, const int* in_sizes, int n_in,
                              void* d_out, int out_size, void* d_ws, size_t ws_size,
                              hipStream_t stream)
{
    const float* nodef      = (const float*)d_in[0];
    const float* ts         = (const float*)d_in[1];
    const float* edgef      = (const float*)d_in[2];
    const int*   neighbors  = (const int*)d_in[3];
    const int*   edge_idxs  = (const int*)d_in[4];
    const float* edge_times = (const float*)d_in[5];
    const float* tw         = (const float*)d_in[6];
    const float* tb         = (const float*)d_in[7];
    const float* W1         = (const float*)d_in[8];
    const float* b1         = (const float*)d_in[9];
    const float* W2         = (const float*)d_in[10];
    const float* b2         = (const float*)d_in[11];
    float*       out        = (float*)d_out;

    const int N = in_sizes[1];          // 30000

    u16*   W1p   = (u16*)d_ws;                          // 12*8*64*8 bf16
    u16*   W2p   = W1p + 12 * 8 * 64 * 8;               // 2*4*8*64*8 bf16
    float* cvec  = (float*)(W2p + 2 * 4 * 8 * 64 * 8);  // [128] f32
    u16*   nfb16 = (u16*)(cvec + DD);                   // [N*128] bf16

    // conversion coverage: total4 float4s, 2 per thread
    int total4     = N * (DD / 4);
    int convThreads = (total4 / 2) + 255;
    int convBlocks  = convThreads / 256;                // ~1875 @ N=30000

    hipLaunchKernelGGL(prep_kernel, dim3(41 + convBlocks), dim3(256), 0, stream,
                       W1, W2, tb, b2, nodef, W1p, W2p, cvec, nfb16, N);
    hipLaunchKernelGGL(fused_all, dim3((N + ROWS - 1) / ROWS), dim3(256), 0, stream,
                       nfb16, ts, edgef, neighbors, edge_idxs, edge_times,
                       tw, tb, W1p, W2p, b1, cvec, out, N);
}

// Round 3
// 472.731 us; speedup vs baseline: 1.0053x; 1.0053x over previous
//
#include <hip/hip_runtime.h>
#include <math.h>

#define DD 128            // feature dim
#define KNB 20            // neighbors per node
#define K3 384            // 3*D
#define ROWS 16           // rows (nodes) per fused block

typedef unsigned short u16;
typedef __attribute__((ext_vector_type(8))) short short8;   // 8 bf16 = 4 VGPRs
typedef __attribute__((ext_vector_type(4))) float f32x4;

// f32 -> bf16 round-to-nearest-even
static __device__ __forceinline__ u16 f2bf(float x) {
    union { float f; unsigned u; } v; v.f = x;
    unsigned r = v.u + 0x7fffu + ((v.u >> 16) & 1u);
    return (u16)(r >> 16);
}

// fast cos: v_fract + v_cos_f32 (input in revolutions). Phase granularity at
// |x|~1e4 rad is ~1.2e-4 rev -> cos abs err ~7.5e-4, far below the bf16
// quantization (0.0625 at magnitude 20) already in the AGG path.
static __device__ __forceinline__ float fcos(float x) {
    float r = x * 0.15915494309189535f;       // 1/(2*pi)
    r = __builtin_amdgcn_fractf(r);
    return __builtin_amdgcn_cosf(r);
}

static __device__ __forceinline__ void st4bf(u16* p, float4 v) {
    ushort4 s;
    s.x = f2bf(v.x); s.y = f2bf(v.y); s.z = f2bf(v.z); s.w = f2bf(v.w);
    *(ushort4*)p = s;
}

// ---------------------------------------------------------------------------
// Prep: blocks 0..39 pack W1 (384x128) and W2 rows 0..255 into MFMA B-fragment
// order (bf16). Block 40 computes cvec[d] = b2[d] + sum_i cos(tb[i])*W2[2D+i][d]
// with 256 threads (two half-sums + LDS combine).
// For 16x16x32: lane L holds B[k0 + (L>>4)*8 + j][ct*16 + (L&15)], j=0..7,
// stored contiguously (16B per lane) at [ktile][ct][L][8].
// ---------------------------------------------------------------------------
__global__ __launch_bounds__(256) void prep_kernel(
    const float* __restrict__ W1, const float* __restrict__ W2,
    const float* __restrict__ tb, const float* __restrict__ b2,
    u16* __restrict__ W1p, u16* __restrict__ W2p, float* __restrict__ cvec)
{
    const int tid = threadIdx.x;
    if (blockIdx.x < 40) {
        int t = blockIdx.x * 256 + tid;
        if (t < 6144) {                       // W1: 12 * 8 * 64
            int L = t & 63;
            int ct = (t >> 6) & 7;
            int kt = t >> 9;
            int n  = ct * 16 + (L & 15);
            int kb = kt * 32 + (L >> 4) * 8;
            u16* d = W1p + (size_t)t * 8;
            #pragma unroll
            for (int j = 0; j < 8; ++j) d[j] = f2bf(W1[(size_t)(kb + j) * DD + n]);
        } else if (t < 10240) {               // W2 parts 0,1: 2 * 4 * 8 * 64
            int u = t - 6144;
            int L = u & 63;
            int ct = (u >> 6) & 7;
            int kt = (u >> 9) & 3;
            int part = u >> 11;
            int n  = ct * 16 + (L & 15);
            int kb = part * DD + kt * 32 + (L >> 4) * 8;
            u16* d = W2p + (size_t)u * 8;
            #pragma unroll
            for (int j = 0; j < 8; ++j) d[j] = f2bf(W2[(size_t)(kb + j) * DD + n]);
        }
    } else {
        __shared__ float red[DD];
        int d = tid & (DD - 1);
        int h = tid >> 7;                     // 0 or 1: each sums 64 terms
        float acc = 0.f;
        int i0 = h * 64;
        #pragma unroll 8
        for (int i = i0; i < i0 + 64; ++i)
            acc = fmaf(cosf(tb[i]), W2[(size_t)(2 * DD + i) * DD + d], acc);
        if (h) red[d] = acc;
        __syncthreads();
        if (!h) cvec[d] = acc + red[d] + b2[d];
    }
}

// ---------------------------------------------------------------------------
// Fused kernel: 16 nodes/block, 256 threads = 4 waves, grid = ceil(N/16).
//  Phase G (gather): 8 groups of 32 lanes; each group owns nodes g and g+8.
//    Per neighbor: 4 independent 512B row gathers (2 node rows, 2 edge rows)
//    + 8 fcos. unroll 5 -> 20 loads in flight per lane (gather is bound by
//    HBM random-row efficiency; keep the controller queues full).
//    Accumulators in registers; results deposited to LDS as bf16 AGG tile
//    [16][384] (pitch APITCH) + NF tile [16][128] (pitch HPITCH).
//  Phase 1: H = relu(AGG @ W1 + 20*b1) -> bf16 back into the AGG LDS region.
//  Phase 2: out = H @ W2[0:128] + NF @ W2[128:256] + cvec.
// No aggbf/nfbf HBM round-trip; no inter-kernel barrier.
// ---------------------------------------------------------------------------
#define APITCH 392      // bf16 elems; 784B rows: 16B-aligned, stride==4 mod 32 banks
#define HPITCH 136      // 272B rows: 16B-aligned, stride==4 mod 32 banks

__global__ __launch_bounds__(256, 4) void fused_all(
    const float* __restrict__ nodef, const float* __restrict__ ts,
    const float* __restrict__ edgef, const int* __restrict__ neighbors,
    const int* __restrict__ edge_idxs, const float* __restrict__ edge_times,
    const float* __restrict__ tw, const float* __restrict__ tb,
    const u16* __restrict__ W1p, const u16* __restrict__ W2p,
    const float* __restrict__ b1, const float* __restrict__ cvec,
    float* __restrict__ out, int N)
{
    __shared__ __align__(16) u16 As[ROWS * APITCH];     // 12544 B; reused as Hs
    __shared__ __align__(16) u16 NFs[ROWS * HPITCH];    //  4352 B
    __shared__ int   s_nb[ROWS * KNB];
    __shared__ int   s_eg[ROWS * KNB];
    __shared__ float s_dt[ROWS * KNB];

    const int tid  = threadIdx.x;
    const int row0 = blockIdx.x * ROWS;

    // ---- stage indices / deltas (coalesced: idx runs contiguously) ----
    for (int idx = tid; idx < ROWS * KNB; idx += 256) {
        int nsub = idx / KNB;
        int k    = idx - nsub * KNB;
        int nn   = row0 + nsub;
        if (nn < N) {
            s_nb[idx] = neighbors[(size_t)nn * KNB + k];
            s_eg[idx] = edge_idxs[(size_t)nn * KNB + k];
            s_dt[idx] = ts[nn] - edge_times[(size_t)nn * KNB + k];
        } else {
            s_nb[idx] = 0; s_eg[idx] = 0; s_dt[idx] = 0.f;
        }
    }
    __syncthreads();

    // ---- phase G: gather + time-encode, 2 interleaved nodes per group ----
    {
        const int c  = tid & 31;
        const int g  = tid >> 5;
        const int ra = g, rb = g + 8;

        const float4* nf4 = (const float4*)nodef;
        const float4* ef4 = (const float4*)edgef;
        const float4  w4  = ((const float4*)tw)[c];
        const float4  b4  = ((const float4*)tb)[c];

        const int*   nba = s_nb + ra * KNB;
        const int*   ega = s_eg + ra * KNB;
        const float* dpa = s_dt + ra * KNB;
        const int*   nbb = s_nb + rb * KNB;
        const int*   egb = s_eg + rb * KNB;
        const float* dpb = s_dt + rb * KNB;

        float4 z = make_float4(0.f, 0.f, 0.f, 0.f);
        float4 ana = z, aea = z, ata = z;
        float4 anb = z, aeb = z, atb = z;

        #pragma unroll 5
        for (int k = 0; k < KNB; ++k) {
            int   nia = nba[k], eia = ega[k];
            int   nib = nbb[k], eib = egb[k];
            float dta = dpa[k], dtb = dpb[k];
            float4 nva = nf4[(size_t)nia * 32 + c];
            float4 eva = ef4[(size_t)eia * 32 + c];
            float4 nvb = nf4[(size_t)nib * 32 + c];
            float4 evb = ef4[(size_t)eib * 32 + c];
            ana.x += nva.x; ana.y += nva.y; ana.z += nva.z; ana.w += nva.w;
            aea.x += eva.x; aea.y += eva.y; aea.z += eva.z; aea.w += eva.w;
            anb.x += nvb.x; anb.y += nvb.y; anb.z += nvb.z; anb.w += nvb.w;
            aeb.x += evb.x; aeb.y += evb.y; aeb.z += evb.z; aeb.w += evb.w;
            ata.x += fcos(fmaf(dta, w4.x, b4.x));
            ata.y += fcos(fmaf(dta, w4.y, b4.y));
            ata.z += fcos(fmaf(dta, w4.z, b4.z));
            ata.w += fcos(fmaf(dta, w4.w, b4.w));
            atb.x += fcos(fmaf(dtb, w4.x, b4.x));
            atb.y += fcos(fmaf(dtb, w4.y, b4.y));
            atb.z += fcos(fmaf(dtb, w4.z, b4.z));
            atb.w += fcos(fmaf(dtb, w4.w, b4.w));
        }

        u16* oa = As + ra * APITCH;
        st4bf(oa + 4 * c,          ana);
        st4bf(oa + DD + 4 * c,     ata);
        st4bf(oa + 2 * DD + 4 * c, aea);
        u16* ob = As + rb * APITCH;
        st4bf(ob + 4 * c,          anb);
        st4bf(ob + DD + 4 * c,     atb);
        st4bf(ob + 2 * DD + 4 * c, aeb);

        // self node-feature rows for phase 2 (separate LDS region)
        int na = row0 + ra;
        float4 sa = (na < N) ? nf4[(size_t)na * 32 + c] : z;
        st4bf(NFs + ra * HPITCH + 4 * c, sa);
        int nb_ = row0 + rb;
        float4 sb = (nb_ < N) ? nf4[(size_t)nb_ * 32 + c] : z;
        st4bf(NFs + rb * HPITCH + 4 * c, sb);
    }
    __syncthreads();

    // ---- phase 1: AGG @ W1 ; wave w owns ct = {2w, 2w+1}, full 16-row M ----
    const int lane = tid & 63;
    const int wave = tid >> 6;
    const int l15  = lane & 15;
    const int quad = lane >> 4;
    const int ct0  = wave * 2;

    f32x4 acc[2];
    acc[0] = (f32x4){0.f, 0.f, 0.f, 0.f};
    acc[1] = (f32x4){0.f, 0.f, 0.f, 0.f};

    const short8* W1v = (const short8*)W1p;
    for (int kt = 0; kt < 12; ++kt) {
        short8 a = *(const short8*)&As[l15 * APITCH + kt * 32 + quad * 8];
        #pragma unroll
        for (int cc = 0; cc < 2; ++cc) {
            short8 b = W1v[(size_t)(kt * 8 + ct0 + cc) * 64 + lane];
            acc[cc] = __builtin_amdgcn_mfma_f32_16x16x32_bf16(a, b, acc[cc], 0, 0, 0);
        }
    }
    __syncthreads();    // all waves done reading As

    // ---- epilogue 1: bias+relu -> Hs (bf16, reuses As region) ----
    u16* Hs = As;
    #pragma unroll
    for (int cc = 0; cc < 2; ++cc) {
        int col = (ct0 + cc) * 16 + l15;
        float bb = (float)KNB * b1[col];
        #pragma unroll
        for (int r = 0; r < 4; ++r) {
            float h = acc[cc][r] + bb;          // C/D: col=lane&15, row=quad*4+r
            h = h > 0.f ? h : 0.f;
            Hs[(quad * 4 + r) * HPITCH + col] = f2bf(h);
        }
    }
    __syncthreads();

    // ---- phase 2: H@W2a + NF@W2b + cvec ----
    f32x4 acc2[2];
    #pragma unroll
    for (int cc = 0; cc < 2; ++cc) {
        float cv = cvec[(ct0 + cc) * 16 + l15];
        acc2[cc] = (f32x4){cv, cv, cv, cv};
    }
    const short8* W2v = (const short8*)W2p;
    for (int kt = 0; kt < 4; ++kt) {
        short8 aH = *(const short8*)&Hs[l15 * HPITCH + kt * 32 + quad * 8];
        #pragma unroll
        for (int cc = 0; cc < 2; ++cc) {
            short8 b = W2v[(size_t)(kt * 8 + ct0 + cc) * 64 + lane];
            acc2[cc] = __builtin_amdgcn_mfma_f32_16x16x32_bf16(aH, b, acc2[cc], 0, 0, 0);
        }
        short8 aN = *(const short8*)&NFs[l15 * HPITCH + kt * 32 + quad * 8];
        #pragma unroll
        for (int cc = 0; cc < 2; ++cc) {
            short8 b = W2v[(size_t)((4 + kt) * 8 + ct0 + cc) * 64 + lane];
            acc2[cc] = __builtin_amdgcn_mfma_f32_16x16x32_bf16(aN, b, acc2[cc], 0, 0, 0);
        }
    }

    // ---- store ----
    #pragma unroll
    for (int cc = 0; cc < 2; ++cc) {
        int col = (ct0 + cc) * 16 + l15;
        #pragma unroll
        for (int r = 0; r < 4; ++r) {
            int row = row0 + quad * 4 + r;
            if (row < N) out[(size_t)row * DD + col] = acc2[cc][r];
        }
    }
}

// ---------------------------------------------------------------------------
extern "C" void kernel_launch(void* const* d_in, const int* in_sizes, int n_in,
                              void* d_out, int out_size, void* d_ws, size_t ws_size,
                              hipStream_t stream)
{
    const float* nodef      = (const float*)d_in[0];
    const float* ts         = (const float*)d_in[1];
    const float* edgef      = (const float*)d_in[2];
    const int*   neighbors  = (const int*)d_in[3];
    const int*   edge_idxs  = (const int*)d_in[4];
    const float* edge_times = (const float*)d_in[5];
    const float* tw         = (const float*)d_in[6];
    const float* tb         = (const float*)d_in[7];
    const float* W1         = (const float*)d_in[8];
    const float* b1         = (const float*)d_in[9];
    const float* W2         = (const float*)d_in[10];
    const float* b2         = (const float*)d_in[11];
    float*       out        = (float*)d_out;

    const int N = in_sizes[1];          // 30000

    u16*   W1p  = (u16*)d_ws;                           // 12*8*64*8 bf16
    u16*   W2p  = W1p + 12 * 8 * 64 * 8;                // 2*4*8*64*8 bf16
    float* cvec = (float*)(W2p + 2 * 4 * 8 * 64 * 8);   // [128] f32

    hipLaunchKernelGGL(prep_kernel, dim3(41), dim3(256), 0, stream,
                       W1, W2, tb, b2, W1p, W2p, cvec);
    hipLaunchKernelGGL(fused_all, dim3((N + ROWS - 1) / ROWS), dim3(256), 0, stream,
                       nodef, ts, edgef, neighbors, edge_idxs, edge_times,
                       tw, tb, W1p, W2p, b1, cvec, out, N);
}